// Round 7
// baseline (312.699 us; speedup 1.0000x reference)
//
#include <hip/hip_runtime.h>
#include <math.h>

#define BATCH 16
#define TOPN 4
#define OUTS 224
#define PADW 224
#define IM 448
#define HP 896
#define NA 1614
#define IC1 2048
#define C128 128

// d_out float offsets
#define N_PART (BATCH*TOPN*3*OUTS*OUTS)       // 9,633,792
#define OFF_TOPIDX  (N_PART)
#define OFF_TOPPROB (N_PART + BATCH*TOPN)
#define OFF_SCORE   (N_PART + 2*BATCH*TOPN)

// ws float offsets.  d1 is [b][px 196][oc 128]
#define WS_D1 0
#define WS_IDX (BATCH*C128*196)                // 64 ints
#define WS_WT  (WS_IDX + 64)                   // repacked weights (ushort)
#define NWT1 (9*2048*128)
#define NWT2 (9*128*128)
#define NRPNT (BATCH*196*IC1)

typedef __attribute__((ext_vector_type(8))) short frag8;     // 8 bf16 (4 VGPRs)
typedef __attribute__((ext_vector_type(16))) float acc16;    // 16 fp32 acc (32x32)
typedef __attribute__((ext_vector_type(4)))  float acc4;     // 4 fp32 acc (16x16)

__device__ __forceinline__ unsigned short f2bf(float f) {
    unsigned int u = __float_as_uint(f);
    u = (u + 0x7fffu + ((u >> 16) & 1u)) >> 16;   // RNE
    return (unsigned short)u;
}
__device__ __forceinline__ float bf2f(unsigned short h) {
    return __uint_as_float(((unsigned int)h) << 16);
}
__device__ __forceinline__ void cvt4(const float* v, ushort4* h, ushort4* lo) {
    unsigned short hh[4], ll[4];
#pragma unroll
    for (int e = 0; e < 4; ++e) { hh[e] = f2bf(v[e]); ll[e] = f2bf(v[e] - bf2f(hh[e])); }
    *h  = make_ushort4(hh[0], hh[1], hh[2], hh[3]);
    *lo = make_ushort4(ll[0], ll[1], ll[2], ll[3]);
}

// swizzled LDS index (in shorts): row stride 80 shorts (160 B = 10x16B),
// 8-short units XOR-swizzled by row -> conflict-free b128 frag reads.
__device__ __forceinline__ int swz(int row, int ic) {
    return row * 80 + ((((ic >> 3) ^ row) & 7) << 3) + (ic & 7);
}

// ---------------- fused prep: wrepack(w1,w2,w3) + rpn transpose + init d1 ----------------
__device__ __forceinline__ void wrepack_body(const float* __restrict__ w,
                                             unsigned short* __restrict__ w_hi,
                                             unsigned short* __restrict__ w_lo,
                                             int IC, int i) {
    if (i >= 128 * IC) return;
    int oc = i / IC, ic = i % IC;
    const float* src = w + (size_t)(oc * IC + ic) * 9;
#pragma unroll
    for (int tap = 0; tap < 9; ++tap) {
        float v = src[tap];
        unsigned short h = f2bf(v);
        size_t gi = ((size_t)tap * 128 + oc) * IC + ic;
        w_hi[gi] = h;
        w_lo[gi] = f2bf(v - bf2f(h));
    }
}

// grid 3232: [0,1024) w1 | [1024,1088) w2 | [1088,1152) w3 | [1152,1664) rpnT | [1664,3232) init_d1
__global__ __launch_bounds__(256) void k_prep(
    const float* __restrict__ w1, unsigned short* __restrict__ w1h, unsigned short* __restrict__ w1l,
    const float* __restrict__ w2, unsigned short* __restrict__ w2h, unsigned short* __restrict__ w2l,
    const float* __restrict__ w3, unsigned short* __restrict__ w3h, unsigned short* __restrict__ w3l,
    const float* __restrict__ rpn, unsigned short* __restrict__ TH, unsigned short* __restrict__ TL,
    const float* __restrict__ b1, float* __restrict__ d1) {
    __shared__ float tile[64 * 201];
    const int tid = threadIdx.x;
    const int blk = blockIdx.x;
    if (blk < 1024) {
        wrepack_body(w1, w1h, w1l, IC1, blk * 256 + tid);
    } else if (blk < 1088) {
        wrepack_body(w2, w2h, w2l, C128, (blk - 1024) * 256 + tid);
    } else if (blk < 1152) {
        wrepack_body(w3, w3h, w3l, C128, (blk - 1088) * 256 + tid);
    } else if (blk < 1664) {
        const int bb = blk - 1152;
        const int b = bb & 15, icg = bb >> 4;
        const int ic0 = icg * 64;
        for (int qq = tid; qq < 3136; qq += 256) {
            int icl = qq / 49, r = qq % 49, p = r * 4;
            const float4 v = *(const float4*)&rpn[(size_t)(b * IC1 + ic0 + icl) * 196 + p];
            tile[icl * 201 + p + 0] = v.x;
            tile[icl * 201 + p + 1] = v.y;
            tile[icl * 201 + p + 2] = v.z;
            tile[icl * 201 + p + 3] = v.w;
        }
        __syncthreads();
        for (int qq = tid; qq < 3136; qq += 256) {
            int px = qq >> 4, ic4 = (qq & 15) * 4;
            float vv[4];
#pragma unroll
            for (int e = 0; e < 4; ++e) vv[e] = tile[(ic4 + e) * 201 + px];
            ushort4 h4, l4; cvt4(vv, &h4, &l4);
            size_t gi = (size_t)(b * 196 + px) * IC1 + ic0 + ic4;
            *(ushort4*)&TH[gi] = h4;
            *(ushort4*)&TL[gi] = l4;
        }
    } else {
        int i = (blk - 1664) * 256 + tid;
        if (i < BATCH * C128 * 196) d1[i] = b1[i & 127];
    }
}

// ---------------- conv1 via MFMA 32x32x16 bf16 (A=input px, B=weight oc) ----------------
// grid 256: blockIdx.x = kg*16 + b; block 512 thr = 8 waves.
// wave w: kgrp = w&1 (16-ic K-split, both groups atomicAdd), wpos = w>>1 ->
//   M-pair {2*wpos, 2*wpos+1} (px tiles of 32) x all 4 N-tiles (oc).
// LDS: stride-80 swizzled (conflict-free).
__global__ __launch_bounds__(512, 2) void k_conv1_mfma(const unsigned short* __restrict__ rpnTH,
                                                       const unsigned short* __restrict__ rpnTL,
                                                       const unsigned short* __restrict__ wt_hi,
                                                       const unsigned short* __restrict__ wt_lo,
                                                       float* __restrict__ d1) {
    __shared__ unsigned short inH[304 * 80];   // [pos][ic64] swizzled
    __shared__ unsigned short inL[304 * 80];
    __shared__ unsigned short wHs[128 * 80];   // [oc][ic64] swizzled
    __shared__ unsigned short wLs[128 * 80];

    const int tid = threadIdx.x;
    const int b = blockIdx.x & 15, kg = blockIdx.x >> 4;
    const int l = tid & 63, w = tid >> 6;
    const int ln = l & 31, q = l >> 5;
    const int kgrp = w & 1, wpos = w >> 1;

    for (int i = tid; i < 304 * 80; i += 512) { inH[i] = 0; inL[i] = 0; }

    acc16 acc[2][4];
#pragma unroll
    for (int mt = 0; mt < 2; ++mt)
#pragma unroll
        for (int nt = 0; nt < 4; ++nt)
#pragma unroll
            for (int r = 0; r < 16; ++r) acc[mt][nt][r] = 0.f;

    int posa[2];
#pragma unroll
    for (int mt = 0; mt < 2; ++mt) {
        int px = (wpos * 2 + mt) * 32 + ln;
        // invalid px -> row 0 (real data, garbage acc, discarded at epilogue)
        posa[mt] = (px < 196) ? ((px / 14 + 1) * 16 + (px % 14 + 1) - 17) : 0;
        // note: pos here is the UN-haloed base; tap offset adds the halo.
        // recompute properly below: use haloed base minus nothing.
        posa[mt] = (px < 196) ? ((px / 14) * 16 + (px % 14)) : 0;
    }
    __syncthreads();

    for (int half = 0; half < 2; ++half) {
        const int ics = kg * 128 + half * 64;
        // stage input from rpnT (vector copy, swizzled store, conflict-free)
        for (int qq = tid; qq < 3136; qq += 512) {
            int px = qq >> 4, ic4 = (qq & 15) * 4;
            size_t gi = (size_t)(b * 196 + px) * IC1 + ics + ic4;
            ushort4 h4 = *(const ushort4*)&rpnTH[gi];
            ushort4 l4 = *(const ushort4*)&rpnTL[gi];
            int pos = (px / 14 + 1) * 16 + (px % 14 + 1);
            *(ushort4*)&inH[swz(pos, ic4)] = h4;
            *(ushort4*)&inL[swz(pos, ic4)] = l4;
        }
        // prefetch tap-0 weights into registers
        ushort4 pwh[4], pwl[4];
#pragma unroll
        for (int it = 0; it < 4; ++it) {
            int qq = tid + it * 512;
            int oc = qq >> 4, ic4 = (qq & 15) * 4;
            size_t gi = ((size_t)(0 * 128 + oc)) * IC1 + ics + ic4;
            pwh[it] = *(const ushort4*)&wt_hi[gi];
            pwl[it] = *(const ushort4*)&wt_lo[gi];
        }
        __syncthreads();

        for (int tap = 0; tap < 9; ++tap) {
#pragma unroll
            for (int it = 0; it < 4; ++it) {
                int qq = tid + it * 512;
                int oc = qq >> 4, ic4 = (qq & 15) * 4;
                *(ushort4*)&wHs[swz(oc, ic4)] = pwh[it];
                *(ushort4*)&wLs[swz(oc, ic4)] = pwl[it];
            }
            if (tap < 8) {
#pragma unroll
                for (int it = 0; it < 4; ++it) {
                    int qq = tid + it * 512;
                    int oc = qq >> 4, ic4 = (qq & 15) * 4;
                    size_t gi = ((size_t)((tap + 1) * 128 + oc)) * IC1 + ics + ic4;
                    pwh[it] = *(const ushort4*)&wt_hi[gi];
                    pwl[it] = *(const ushort4*)&wt_lo[gi];
                }
            }
            __syncthreads();

            const int off = (tap / 3) * 16 + (tap % 3);
#pragma unroll
            for (int c = 0; c < 2; ++c) {
                const int ko = kgrp * 32 + c * 16 + q * 8;
                frag8 aH[2], aL[2], bH[4], bL[4];
#pragma unroll
                for (int mt = 0; mt < 2; ++mt) {
                    int idx = swz(posa[mt] + off, ko);
                    aH[mt] = *(const frag8*)&inH[idx];
                    aL[mt] = *(const frag8*)&inL[idx];
                }
#pragma unroll
                for (int nt = 0; nt < 4; ++nt) {
                    int idx = swz(nt * 32 + ln, ko);
                    bH[nt] = *(const frag8*)&wHs[idx];
                    bL[nt] = *(const frag8*)&wLs[idx];
                }
#pragma unroll
                for (int mt = 0; mt < 2; ++mt)
#pragma unroll
                    for (int nt = 0; nt < 4; ++nt) {
                        acc[mt][nt] = __builtin_amdgcn_mfma_f32_32x32x16_bf16(aH[mt], bH[nt], acc[mt][nt], 0, 0, 0);
                        acc[mt][nt] = __builtin_amdgcn_mfma_f32_32x32x16_bf16(aH[mt], bL[nt], acc[mt][nt], 0, 0, 0);
                        acc[mt][nt] = __builtin_amdgcn_mfma_f32_32x32x16_bf16(aL[mt], bH[nt], acc[mt][nt], 0, 0, 0);
                    }
            }
            __syncthreads();
        }
    }

    // epilogue: both K-groups atomicAdd (split-K reduce via atomics), coalesced on oc
#pragma unroll
    for (int mt = 0; mt < 2; ++mt)
#pragma unroll
        for (int nt = 0; nt < 4; ++nt) {
            int oc = nt * 32 + ln;
#pragma unroll
            for (int r = 0; r < 16; ++r) {
                int m = (r & 3) + 8 * (r >> 2) + 4 * q;
                int px = (wpos * 2 + mt) * 32 + m;
                if (px < 196)
                    atomicAdd(&d1[(size_t)(b * 196 + px) * 128 + oc], acc[mt][nt][r]);
            }
        }
}

// NOTE: the A-frag halo: staging writes at pos = (px/14+1)*16 + (px%14+1); frag reads use
// posa (un-haloed) + off where off = (tap/3)*16 + (tap%3). For tap (1,1) (off=17) this
// reproduces the haloed center exactly; rows outside stay zero-initialized.

// ---------------- fused tail: conv2+conv3+tidy+NMS, one 512-thread block per batch -------
__global__ __launch_bounds__(512, 1) void k_tail(
    const float* __restrict__ d1,
    const unsigned short* __restrict__ w2h, const unsigned short* __restrict__ w2l,
    const unsigned short* __restrict__ w3h, const unsigned short* __restrict__ w3l,
    const float* __restrict__ b2, const float* __restrict__ b3,
    const float* __restrict__ wt1, const float* __restrict__ bt1,
    const float* __restrict__ wt2, const float* __restrict__ bt2,
    const float* __restrict__ wt3, const float* __restrict__ bt3,
    const int* __restrict__ anchors,
    float* __restrict__ score_out, float* __restrict__ out_idx,
    float* __restrict__ out_prob, int* __restrict__ idx_ws) {
    extern __shared__ char smem[];
    unsigned short* inH = (unsigned short*)(smem);            // [pos 304][ic 72]
    unsigned short* inL = (unsigned short*)(smem + 43776);
    unsigned short* wHs = (unsigned short*)(smem + 87552);    // [oc 128][ic 72]
    unsigned short* wLs = (unsigned short*)(smem + 105984);
    unsigned short* t1H = (unsigned short*)(smem + 124416);   // [oc16][ic 72]
    unsigned short* t1L = (unsigned short*)(smem + 126720);
    float*  d2f  = (float*)(smem + 129024);                   // [px 49][oc 128]
    float*  sbuf = (float*)(smem + 154112);                   // [1614]
    unsigned short* dhH = (unsigned short*)(smem);            // [pos 192][ic 72]
    unsigned short* dhL = (unsigned short*)(smem + 27648);
    float*  d3f  = (float*)(smem + 55296);                    // [oc 128][px 16]
    unsigned short* t2H = (unsigned short*)(smem + 63488);
    unsigned short* t2L = (unsigned short*)(smem + 65792);
    unsigned short* w3H = (unsigned short*)(smem + 68096);
    unsigned short* w3L = (unsigned short*)(smem + 86528);
    float* wt3s = (float*)(smem);
    float* y0s = (float*)(smem + 6464);
    float* x0s = (float*)(smem + 12928);
    float* y1s = (float*)(smem + 19392);
    float* x1s = (float*)(smem + 25856);
    float* ars = (float*)(smem + 32320);
    float* rv  = (float*)(smem + 38784);
    int*   ri  = (int*)(smem + 39808);

    const int tid = threadIdx.x;           // 0..511, 8 waves
    const int b = blockIdx.x;
    const int l = tid & 63, w = tid >> 6;
    const int ln = l & 31, q = l >> 5;
    const int l16 = l & 15, q4 = l >> 4;

    // ================= phase A: conv2 + t1 =================
    for (int i = tid; i < 304 * 72; i += 512) { inH[i] = 0; inL[i] = 0; }

    acc16 c2;
    acc4 t1a[2];
#pragma unroll
    for (int r = 0; r < 16; ++r) c2[r] = 0.f;
#pragma unroll
    for (int i = 0; i < 2; ++i)
#pragma unroll
        for (int r = 0; r < 4; ++r) t1a[i][r] = 0.f;

    const int mtw = w & 1, ntw = w >> 1;   // 2 px-tiles x 4 oc-tiles
    int posa2;
    {
        int px = mtw * 32 + ln;
        posa2 = (px < 49) ? ((px / 7) * 32 + (px % 7) * 2) : 256;
    }
    __syncthreads();

    for (int half = 0; half < 2; ++half) {
        const int ics = half * 64;
        for (int qq = tid; qq < 3136; qq += 512) {
            int px = qq >> 4, ic4 = (qq & 15) * 4;
            float4 v = *(const float4*)&d1[(size_t)(b * 196 + px) * 128 + ics + ic4];
            float vv[4] = {fmaxf(v.x, 0.f), fmaxf(v.y, 0.f), fmaxf(v.z, 0.f), fmaxf(v.w, 0.f)};
            ushort4 h4, l4; cvt4(vv, &h4, &l4);
            int pos = (px / 14 + 1) * 16 + (px % 14 + 1);
            *(ushort4*)&inH[pos * 72 + ic4] = h4;
            *(ushort4*)&inL[pos * 72 + ic4] = l4;
        }
        for (int qq = tid; qq < 1024; qq += 512) {
            int m = qq >> 6, k = qq & 63;
            float v = (m < 6) ? wt1[m * 128 + ics + k] : 0.f;
            unsigned short h = f2bf(v);
            t1H[m * 72 + k] = h;
            t1L[m * 72 + k] = f2bf(v - bf2f(h));
        }
        // prefetch tap-0 conv2 weights
        ushort4 pwh[4], pwl[4];
#pragma unroll
        for (int it = 0; it < 4; ++it) {
            int qq = tid + it * 512;
            int oc = qq >> 4, ic4 = (qq & 15) * 4;
            size_t gi = ((size_t)(0 * 128 + oc)) * C128 + ics + ic4;
            pwh[it] = *(const ushort4*)&w2h[gi];
            pwl[it] = *(const ushort4*)&w2l[gi];
        }
        __syncthreads();

        for (int tap = 0; tap < 9; ++tap) {
#pragma unroll
            for (int it = 0; it < 4; ++it) {
                int qq = tid + it * 512;
                int oc = qq >> 4, ic4 = (qq & 15) * 4;
                *(ushort4*)&wHs[oc * 72 + ic4] = pwh[it];
                *(ushort4*)&wLs[oc * 72 + ic4] = pwl[it];
            }
            if (tap < 8) {
#pragma unroll
                for (int it = 0; it < 4; ++it) {
                    int qq = tid + it * 512;
                    int oc = qq >> 4, ic4 = (qq & 15) * 4;
                    size_t gi = ((size_t)((tap + 1) * 128 + oc)) * C128 + ics + ic4;
                    pwh[it] = *(const ushort4*)&w2h[gi];
                    pwl[it] = *(const ushort4*)&w2l[gi];
                }
            }
            __syncthreads();
            const int off = (tap / 3) * 16 + (tap % 3);
#pragma unroll
            for (int c = 0; c < 4; ++c) {
                const int ko = c * 16 + q * 8;
                int pp = (posa2 + off) * 72 + ko;
                frag8 aH = *(const frag8*)&inH[pp];
                frag8 aL = *(const frag8*)&inL[pp];
                int oc = ntw * 32 + ln;
                frag8 bH = *(const frag8*)&wHs[oc * 72 + ko];
                frag8 bL = *(const frag8*)&wLs[oc * 72 + ko];
                c2 = __builtin_amdgcn_mfma_f32_32x32x16_bf16(aH, bH, c2, 0, 0, 0);
                c2 = __builtin_amdgcn_mfma_f32_32x32x16_bf16(aH, bL, c2, 0, 0, 0);
                c2 = __builtin_amdgcn_mfma_f32_32x32x16_bf16(aL, bH, c2, 0, 0, 0);
            }
            __syncthreads();
        }

        // t1 MFMA on this half (inH intact since last barrier)
#pragma unroll
        for (int i = 0; i < 2; ++i) {
            int px = (w * 2 + i) * 16 + l16;
            int pos = (px < 196) ? ((px / 14 + 1) * 16 + (px % 14 + 1)) : 256;
#pragma unroll
            for (int c = 0; c < 2; ++c) {
                int ko = c * 32 + q4 * 8;
                frag8 aH = *(const frag8*)&t1H[l16 * 72 + ko];
                frag8 aL = *(const frag8*)&t1L[l16 * 72 + ko];
                frag8 bH = *(const frag8*)&inH[pos * 72 + ko];
                frag8 bL = *(const frag8*)&inL[pos * 72 + ko];
                t1a[i] = __builtin_amdgcn_mfma_f32_16x16x32_bf16(aH, bH, t1a[i], 0, 0, 0);
                t1a[i] = __builtin_amdgcn_mfma_f32_16x16x32_bf16(aH, bL, t1a[i], 0, 0, 0);
                t1a[i] = __builtin_amdgcn_mfma_f32_16x16x32_bf16(aL, bH, t1a[i], 0, 0, 0);
            }
        }
        __syncthreads();
    }

    // conv2 epilogue -> d2f[px][oc]
    {
        int oc = ntw * 32 + ln;
        float bias = b2[oc];
#pragma unroll
        for (int r = 0; r < 16; ++r) {
            int m = (r & 3) + 8 * (r >> 2) + 4 * q;
            int px = mtw * 32 + m;
            if (px < 49) d2f[px * 128 + oc] = fmaxf(c2[r] + bias, 0.f);
        }
    }
    // t1 epilogue -> scores
#pragma unroll
    for (int i = 0; i < 2; ++i) {
        int px = (w * 2 + i) * 16 + l16;
#pragma unroll
        for (int r = 0; r < 4; ++r) {
            int oc = q4 * 4 + r;
            if (oc < 6 && px < 196) {
                float v = t1a[i][r] + bt1[oc];
                sbuf[oc * 196 + px] = v;
                score_out[b * NA + oc * 196 + px] = v;
            }
        }
    }
    __syncthreads();

    // ================= phase B: conv3 (waves 0-3) + t2 (waves 4-7) =================
    for (int i = tid; i < 192 * 72; i += 512) { dhH[i] = 0; dhL[i] = 0; }

    acc16 c3;
    acc4 t2a;
#pragma unroll
    for (int r = 0; r < 16; ++r) c3[r] = 0.f;
#pragma unroll
    for (int r = 0; r < 4; ++r) t2a[r] = 0.f;

    const int posb3 = (ln < 16) ? ((ln / 4) * 32 + (ln % 4) * 2) : 144;
    const int pxt2 = (w - 4) * 16 + l16;   // valid for w>=4
    const int posbt2 = (w >= 4 && pxt2 < 49) ? ((pxt2 / 7 + 1) * 16 + (pxt2 % 7 + 1)) : 144;
    __syncthreads();

    for (int half = 0; half < 2; ++half) {
        const int ics = half * 64;
        for (int qq = tid; qq < 784; qq += 512) {
            int px = qq >> 4, ic4 = (qq & 15) * 4;
            float4 v = *(const float4*)&d2f[px * 128 + ics + ic4];
            float vv[4] = {v.x, v.y, v.z, v.w};
            ushort4 h4, l4; cvt4(vv, &h4, &l4);
            int pos = (px / 7 + 1) * 16 + (px % 7 + 1);
            *(ushort4*)&dhH[pos * 72 + ic4] = h4;
            *(ushort4*)&dhL[pos * 72 + ic4] = l4;
        }
        for (int qq = tid; qq < 1024; qq += 512) {
            int m = qq >> 6, k = qq & 63;
            float v = (m < 6) ? wt2[m * 128 + ics + k] : 0.f;
            unsigned short h = f2bf(v);
            t2H[m * 72 + k] = h;
            t2L[m * 72 + k] = f2bf(v - bf2f(h));
        }
        ushort4 pwh[4], pwl[4];
#pragma unroll
        for (int it = 0; it < 4; ++it) {
            int qq = tid + it * 512;
            int oc = qq >> 4, ic4 = (qq & 15) * 4;
            size_t gi = ((size_t)(0 * 128 + oc)) * C128 + ics + ic4;
            pwh[it] = *(const ushort4*)&w3h[gi];
            pwl[it] = *(const ushort4*)&w3l[gi];
        }
        __syncthreads();

        for (int tap = 0; tap < 9; ++tap) {
#pragma unroll
            for (int it = 0; it < 4; ++it) {
                int qq = tid + it * 512;
                int oc = qq >> 4, ic4 = (qq & 15) * 4;
                *(ushort4*)&w3H[oc * 72 + ic4] = pwh[it];
                *(ushort4*)&w3L[oc * 72 + ic4] = pwl[it];
            }
            if (tap < 8) {
#pragma unroll
                for (int it = 0; it < 4; ++it) {
                    int qq = tid + it * 512;
                    int oc = qq >> 4, ic4 = (qq & 15) * 4;
                    size_t gi = ((size_t)((tap + 1) * 128 + oc)) * C128 + ics + ic4;
                    pwh[it] = *(const ushort4*)&w3h[gi];
                    pwl[it] = *(const ushort4*)&w3l[gi];
                }
            }
            __syncthreads();
            const int off = (tap / 3) * 16 + (tap % 3);
            if (w < 4) {
#pragma unroll
                for (int c = 0; c < 4; ++c) {
                    const int ko = c * 16 + q * 8;
                    int pp = (posb3 + off) * 72 + ko;
                    frag8 aH = *(const frag8*)&dhH[pp];
                    frag8 aL = *(const frag8*)&dhL[pp];
                    int oc = w * 32 + ln;
                    frag8 bH = *(const frag8*)&w3H[oc * 72 + ko];
                    frag8 bL = *(const frag8*)&w3L[oc * 72 + ko];
                    c3 = __builtin_amdgcn_mfma_f32_32x32x16_bf16(aH, bH, c3, 0, 0, 0);
                    c3 = __builtin_amdgcn_mfma_f32_32x32x16_bf16(aH, bL, c3, 0, 0, 0);
                    c3 = __builtin_amdgcn_mfma_f32_32x32x16_bf16(aL, bH, c3, 0, 0, 0);
                }
            } else if (tap == 0) {
                // t2 on this half (dh is stable during the tap loop)
#pragma unroll
                for (int c = 0; c < 2; ++c) {
                    int ko = c * 32 + q4 * 8;
                    frag8 aH = *(const frag8*)&t2H[l16 * 72 + ko];
                    frag8 aL = *(const frag8*)&t2L[l16 * 72 + ko];
                    frag8 bH = *(const frag8*)&dhH[posbt2 * 72 + ko];
                    frag8 bL = *(const frag8*)&dhL[posbt2 * 72 + ko];
                    t2a = __builtin_amdgcn_mfma_f32_16x16x32_bf16(aH, bH, t2a, 0, 0, 0);
                    t2a = __builtin_amdgcn_mfma_f32_16x16x32_bf16(aH, bL, t2a, 0, 0, 0);
                    t2a = __builtin_amdgcn_mfma_f32_16x16x32_bf16(aL, bH, t2a, 0, 0, 0);
                }
            }
            __syncthreads();
        }
    }

    // conv3 epilogue -> d3f[oc][px]
    if (w < 4) {
        int oc = w * 32 + ln;
        float bias = b3[oc];
#pragma unroll
        for (int r = 0; r < 16; ++r) {
            int px = (r & 3) + 8 * (r >> 2) + 4 * q;
            if (px < 16) d3f[oc * 16 + px] = fmaxf(c3[r] + bias, 0.f);
        }
    } else {
        // t2 epilogue -> scores
#pragma unroll
        for (int r = 0; r < 4; ++r) {
            int oc = q4 * 4 + r;
            if (oc < 6 && pxt2 < 49) {
                float v = t2a[r] + bt2[oc];
                sbuf[1176 + oc * 49 + pxt2] = v;
                score_out[b * NA + 1176 + oc * 49 + pxt2] = v;
            }
        }
    }
    for (int i = tid; i < 1152; i += 512) wt3s[i] = wt3[i];
    __syncthreads();

    // ================= phase C: t3 (VALU) + anchor staging =================
    if (tid < 144) {
        int oc = tid >> 4, px = tid & 15;
        float s = bt3[oc];
        for (int ic = 0; ic < 128; ++ic) s += wt3s[oc * 128 + ic] * d3f[ic * 16 + px];
        sbuf[1470 + oc * 16 + px] = s;
        score_out[b * NA + 1470 + oc * 16 + px] = s;
    }
    for (int j = tid; j < NA; j += 512) {
        int4 a = ((const int4*)anchors)[j];
        float a0 = (float)a.x, a1 = (float)a.y, a2 = (float)a.z, a3 = (float)a.w;
        y0s[j] = a0; x0s[j] = a1; y1s[j] = a2; x1s[j] = a3;
        ars[j] = (a2 - a0) * (a3 - a1);
    }
    __syncthreads();

    // ================= phase D: greedy hard-NMS top-4 (shuffle reduce) =================
    for (int it = 0; it < TOPN; ++it) {
        float bv = -INFINITY; int bi = NA;
        for (int j = tid; j < NA; j += 512) {
            float v = sbuf[j];
            if (v > bv || (v == bv && j < bi)) { bv = v; bi = j; }
        }
#pragma unroll
        for (int d = 1; d < 64; d <<= 1) {
            float ov = __shfl_xor(bv, d, 64);
            int   oi = __shfl_xor(bi, d, 64);
            if (ov > bv || (ov == bv && oi < bi)) { bv = ov; bi = oi; }
        }
        if (l == 0) { rv[w] = bv; ri[w] = bi; }
        __syncthreads();
        if (tid == 0) {
            float V = rv[0]; int K = ri[0];
#pragma unroll
            for (int j = 1; j < 8; ++j) {
                float ov = rv[j]; int oi = ri[j];
                if (ov > V || (ov == V && oi < K)) { V = ov; K = oi; }
            }
            ri[8] = K;
            out_idx[b * TOPN + it] = (float)K;
            out_prob[b * TOPN + it] = V;
            idx_ws[b * TOPN + it] = K;
        }
        __syncthreads();
        int K = ri[8];
        float ky0 = y0s[K], kx0 = x0s[K], ky1 = y1s[K], kx1 = x1s[K], ka = ars[K];
        for (int j = tid; j < NA; j += 512) {
            float iy = fmaxf(fminf(y1s[j], ky1) - fmaxf(y0s[j], ky0), 0.f);
            float ix = fmaxf(fminf(x1s[j], kx1) - fmaxf(x0s[j], kx0), 0.f);
            float inter = iy * ix;
            float iou = inter / (ars[j] + ka - inter);
            if (iou >= 0.25f) sbuf[j] = -INFINITY;
        }
        __syncthreads();
    }
}

// ---------------- bilinear crop-resize ----------------
__global__ __launch_bounds__(256) void k_crop(const float* __restrict__ x,
                                              const int* __restrict__ anchors,
                                              const int* __restrict__ idx_ws,
                                              float* __restrict__ out) {
    int blk = blockIdx.x;
    int crop = blk / OUTS;
    int i = blk % OUTS;
    int j = threadIdx.x;
    if (j >= OUTS) return;
    int b = crop >> 2;
    int a = idx_ws[crop];
    int y0 = anchors[a * 4], x0 = anchors[a * 4 + 1];
    int y1 = anchors[a * 4 + 2], x1 = anchors[a * 4 + 3];

    float ti = (float)i / 223.f;
    float ys = (float)y0 + ti * (float)(y1 - y0 - 1);
    int yi0 = (int)ys;
    int yi1 = min(yi0 + 1, HP - 1);
    float wy = ys - (float)yi0;

    float tj = (float)j / 223.f;
    float xs = (float)x0 + tj * (float)(x1 - x0 - 1);
    int xi0 = (int)xs;
    int xi1 = min(xi0 + 1, HP - 1);
    float wx = xs - (float)xi0;

    int ry0 = yi0 - PADW, ry1 = yi1 - PADW, rx0 = xi0 - PADW, rx1 = xi1 - PADW;
    bool vy0 = (ry0 >= 0) && (ry0 < IM), vy1 = (ry1 >= 0) && (ry1 < IM);
    bool vx0 = (rx0 >= 0) && (rx0 < IM), vx1 = (rx1 >= 0) && (rx1 < IM);

    float w00 = (1.f - wy) * (1.f - wx), w01 = (1.f - wy) * wx;
    float w10 = wy * (1.f - wx), w11 = wy * wx;

#pragma unroll
    for (int c = 0; c < 3; ++c) {
        const float* xp = x + (size_t)(b * 3 + c) * IM * IM;
        float g00 = (vy0 && vx0) ? xp[ry0 * IM + rx0] : 0.f;
        float g01 = (vy0 && vx1) ? xp[ry0 * IM + rx1] : 0.f;
        float g10 = (vy1 && vx0) ? xp[ry1 * IM + rx0] : 0.f;
        float g11 = (vy1 && vx1) ? xp[ry1 * IM + rx1] : 0.f;
        out[(size_t)(crop * 3 + c) * OUTS * OUTS + i * OUTS + j] =
            g00 * w00 + g01 * w01 + g10 * w10 + g11 * w11;
    }
}

extern "C" void kernel_launch(void* const* d_in, const int* in_sizes, int n_in,
                              void* d_out, int out_size, void* d_ws, size_t ws_size,
                              hipStream_t stream) {
    (void)in_sizes; (void)n_in; (void)out_size; (void)ws_size;
    const float* x    = (const float*)d_in[0];
    const float* rpn  = (const float*)d_in[1];
    const float* w1   = (const float*)d_in[2];
    const float* b1   = (const float*)d_in[3];
    const float* w2   = (const float*)d_in[4];
    const float* b2   = (const float*)d_in[5];
    const float* w3   = (const float*)d_in[6];
    const float* b3   = (const float*)d_in[7];
    const float* wt1  = (const float*)d_in[8];
    const float* bt1  = (const float*)d_in[9];
    const float* wt2  = (const float*)d_in[10];
    const float* bt2  = (const float*)d_in[11];
    const float* wt3  = (const float*)d_in[12];
    const float* bt3  = (const float*)d_in[13];
    const int*   anc  = (const int*)d_in[14];

    float* out = (float*)d_out;
    float* ws  = (float*)d_ws;
    float* d1  = ws + WS_D1;
    int*   idxw = (int*)(ws + WS_IDX);
    unsigned short* w1h = (unsigned short*)(ws + WS_WT);
    unsigned short* w1l = w1h + NWT1;
    unsigned short* w2h = w1l + NWT1;
    unsigned short* w2l = w2h + NWT2;
    unsigned short* w3h = w2l + NWT2;
    unsigned short* w3l = w3h + NWT2;
    unsigned short* rpnTH = w3l + NWT2;
    unsigned short* rpnTL = rpnTH + NRPNT;

    static const int TAIL_LDS = 160568;
    hipFuncSetAttribute((const void*)k_tail, hipFuncAttributeMaxDynamicSharedMemorySize, TAIL_LDS);

    k_prep<<<3232, 256, 0, stream>>>(w1, w1h, w1l, w2, w2h, w2l, w3, w3h, w3l,
                                     rpn, rpnTH, rpnTL, b1, d1);
    k_conv1_mfma<<<256, 512, 0, stream>>>(rpnTH, rpnTL, w1h, w1l, d1);
    k_tail<<<BATCH, 512, TAIL_LDS, stream>>>(d1, w2h, w2l, w3h, w3l, b2, b3,
                                             wt1, bt1, wt2, bt2, wt3, bt3, anc,
                                             out + OFF_SCORE, out + OFF_TOPIDX,
                                             out + OFF_TOPPROB, idxw);
    k_crop<<<BATCH * TOPN * OUTS, 256, 0, stream>>>(x, anc, idxw, out);
}